// Round 12
// baseline (216.736 us; speedup 1.0000x reference)
//
#include <hip/hip_runtime.h>

#define SIG 2.8853900817779268f   // 2*log2(e)
#define INV_SIG3 (1.0f/(SIG*SIG*SIG))

typedef float float2v __attribute__((ext_vector_type(2)));

__device__ __forceinline__ float rcp_f (float x){ return __builtin_amdgcn_rcpf(x);  }
__device__ __forceinline__ float exp2_f(float x){ return __builtin_amdgcn_exp2f(x); }
__device__ __forceinline__ float2v fma2(float2v a, float2v b, float2v c){
    return __builtin_elementwise_fma(a, b, c);   // -> v_pk_fma_f32
}

// permuted column pair j (0..7): original units (4*(j/2)+(j&1), +2)
#define KC0(j) (4*((j)>>1) + ((j)&1))
#define KC1(j) (KC0(j) + 2)
#define LD2(base, j) ((float2v){ (base)[KC0(j)], (base)[KC1(j)] })

// One r-iteration body (r9 structure). Uses running spc2/spd2/mulT/r.
#define CBODY() do {                                                              \
    const float2v* frow2 = (const float2v*)(fW1 + (r << 4)); /* uniform */        \
    float2v s2p = {0.f, 0.f};                                                     \
    _Pragma("unroll")                                                             \
    for (int q = 0; q < 4; ++q) {                                                 \
        const float2v tP = fma2(spd2, LD2(W8r, 2*q),                              \
                                fma2(spc2, LD2(W7r, 2*q), AB2[2*q]));             \
        const float2v tQ = fma2(spd2, LD2(W8r, 2*q+1),                            \
                                fma2(spc2, LD2(W7r, 2*q+1), AB2[2*q+1]));         \
        const float2v eP = (float2v){ exp2_f(tP.x), exp2_f(tP.y) } + 1.f;         \
        const float2v eQ = (float2v){ exp2_f(tQ.x), exp2_f(tQ.y) } + 1.f;         \
        const float2v W2P = LD2(W2, 2*q), W2Q = LD2(W2, 2*q+1);                   \
        const float2v npair = fma2(W2Q, eP, W2P * eQ);                            \
        const float2v dpair = eP * eQ;                                            \
        const float2v rpair = { rcp_f(dpair.x), rcp_f(dpair.y) };                 \
        s2p = fma2(npair, rpair, s2p);                                            \
    }                                                                             \
    const float mulnn = fmaf(-2.f, s2p.x + s2p.y, C2);                            \
    Lsum += fabsf(mulT - mulnn);                                                  \
    const float2v mul2 = {mulnn, mulnn};                                          \
    _Pragma("unroll")                                                             \
    for (int j = 0; j < 8; ++j) acc2[j] = fma2(mul2, frow2[j], acc2[j]);          \
    spc2 *= w2v;                                                                  \
    spd2 *= rz2v;                                                                 \
    mulT *= wz;                                                                   \
    ++r;                                                                          \
} while (0)

// A full (a,b) cell with compile-time trip count K+1 -> straight-line code,
// compiler can hoist/pipeline exp2s across iterations.
#define CELL(K) { _Pragma("unroll") for (int ci = 0; ci <= (K); ++ci) { CBODY(); } }

// Block: 448 threads = 7 waves; wave s handles permutation s for 64 consecutive m.
__global__ __launch_bounds__(448) void maron_kernel(
    const float* __restrict__ x,      // (64,14,1024)
    const float* __restrict__ W1,     // (14,16)
    const float* __restrict__ b1,     // (16)
    const float* __restrict__ W2,     // (16,1)
    const float* __restrict__ b2p,    // (1)
    const float* __restrict__ fW1,    // (120,16)
    const float* __restrict__ fb1,    // (16)
    const float* __restrict__ fW2,    // (16,1)
    const float* __restrict__ fb2p,   // (1)
    float* __restrict__ out,          // (M) out ++ (M) L
    int M)
{
    __shared__ float red[7][64][17];  // stride 17 (odd) -> conflict-free

    const int tid = threadIdx.x;
    const int s   = tid >> 6;         // 0..6 (wave-uniform)
    const int ml  = tid & 63;
    const int m   = blockIdx.x * 64 + ml;
    const int bb  = m >> 10, tt = m & 1023;

    const float* xb = x + (size_t)bb * 14 * 1024 + tt;
    const int i0 = (7 - s) % 7;
    const int i1 = (8 - s) % 7;

    const float u = xb[(i0    ) * 1024];
    const float v = xb[(i1    ) * 1024];
    const float w = xb[(7 + i0) * 1024];
    float z = fmaxf(xb[(7 + i1) * 1024], 3.814697265625e-6f);  // 2^-18
    const float rz = rcp_f(z);
    const float wz = w * rz;

    const float* W1r1 = W1 + 1*16;
    const float* W7r  = W1 + 7*16;
    const float* W8r  = W1 + 8*16;

    float C2 = b2p[0];
#pragma unroll
    for (int k = 0; k < 16; ++k) C2 += W2[k];

    // AB2[j] = SIG*(b1 + sum_{rows != 7,8} W1[row,k]*p_row), permuted pair layout.
    float2v AB2[8];
#pragma unroll
    for (int j = 0; j < 8; ++j) {
        float2v t;
#pragma unroll
        for (int h = 0; h < 2; ++h) {
            const int k = KC0(j) + 2*h;
            float tt2 = b1[k] + W1[0*16+k] + W1[1*16+k];
            tt2 += W1[2*16+k] + W1[3*16+k] + W1[4*16+k] + W1[5*16+k] + W1[6*16+k];
            tt2 += W1[9*16+k] + W1[10*16+k] + W1[11*16+k] + W1[12*16+k] + W1[13*16+k];
            t[h] = SIG * tt2;
        }
        AB2[j] = t;
    }

    float2v acc2[8];
#pragma unroll
    for (int j = 0; j < 8; ++j) acc2[j] = (float2v){0.f, 0.f};
    float Lsum = 0.f;

    const float z2t = z * z, z4t = z2t * z2t;
    float zna = SIG * (z4t * z2t * z);  // SIG * z^(7-a)
    float spa = SIG;                    // SIG * u^a
    float spb = SIG;                    // SIG * v^b
    float znb = zna;                    // SIG * z^(7-a-b)

    const float2v w2v  = {w,  w};
    const float2v rz2v = {rz, rz};

    int r = 0;
    for (int a = 0; a <= 7; ++a) {
        for (int bi = 0; bi <= 7 - a; ++bi) {
            const int cmax = 7 - a - bi;
            float2v spc2 = {SIG, SIG};          // SIG * w^c
            float2v spd2 = {znb, znb};          // SIG * z^d
            float mulT = ((spa * spb) * znb) * INV_SIG3;  // u^a v^b w^c z^d

            switch (cmax) {
                case 0: CELL(0); break;
                case 1: CELL(1); break;
                case 2: CELL(2); break;
                case 3: CELL(3); break;
                case 4: CELL(4); break;
                case 5: CELL(5); break;
                case 6: CELL(6); break;
                default: CELL(7); break;
            }

            // b -> b+1
            const float dspb = spb * (v - 1.f);
            const float2v dspb2 = {dspb, dspb};
#pragma unroll
            for (int j = 0; j < 8; ++j) AB2[j] = fma2(dspb2, LD2(W1r1, j), AB2[j]);
            spb *= v;
            znb *= rz;
        }
        // a -> a+1 (reset b-contribution to SIG)
        const float dspa = spa * (u - 1.f);
        const float dB   = SIG - spb;
        const float2v dspa2 = {dspa, dspa};
        const float2v dB2   = {dB,   dB};
#pragma unroll
        for (int j = 0; j < 8; ++j)
            AB2[j] = fma2(dspa2, LD2(W1, j), fma2(dB2, LD2(W1r1, j), AB2[j]));
        spa *= u;
        zna *= rz;
        spb = SIG;
        znb = zna;
    }

#pragma unroll
    for (int j = 0; j < 8; ++j) {
        red[s][ml][2*j]   = acc2[j].x;
        red[s][ml][2*j+1] = acc2[j].y;
    }
    red[s][ml][16] = Lsum;
    __syncthreads();

    // parallel 7-way reduction: 64*17 slots over 448 threads
    for (int p = tid; p < 64 * 17; p += 448) {
        const int kk = p >> 6;
        const int mm = p & 63;
        float t = red[0][mm][kk];
#pragma unroll
        for (int ss = 1; ss < 7; ++ss) t += red[ss][mm][kk];
        red[0][mm][kk] = t;
    }
    __syncthreads();

    if (tid < 64) {
        float o = fb2p[0];
        float s3 = 0.f;
#pragma unroll
        for (int k = 0; k < 16; ++k) {
            const float a2 = SIG * (red[0][tid][k] + fb1[k]);
            const float rk = rcp_f(exp2_f(a2) + 1.f);
            s3 = fmaf(fW2[k], rk, s3);
            o += fW2[k];
        }
        o = fmaf(-2.f, s3, o);

        const int mo = blockIdx.x * 64 + tid;
        out[mo]     = o;
        out[M + mo] = red[0][tid][16] * (1.f / 120.f);
    }
}

extern "C" void kernel_launch(void* const* d_in, const int* in_sizes, int n_in,
                              void* d_out, int out_size, void* d_ws, size_t ws_size,
                              hipStream_t stream) {
    const float* x   = (const float*)d_in[0];
    const float* W1  = (const float*)d_in[1];
    const float* b1  = (const float*)d_in[2];
    const float* W2  = (const float*)d_in[3];
    const float* b2  = (const float*)d_in[4];
    const float* fW1 = (const float*)d_in[5];
    const float* fb1 = (const float*)d_in[6];
    const float* fW2 = (const float*)d_in[7];
    const float* fb2 = (const float*)d_in[8];

    const int M = out_size / 2;           // 65536
    const int blocks = M / 64;            // 1024

    maron_kernel<<<blocks, 448, 0, stream>>>(x, W1, b1, W2, b2, fW1, fb1, fW2, fb2,
                                             (float*)d_out, M);
}

// Round 13
// 199.440 us; speedup vs baseline: 1.0867x; 1.0867x over previous
//
#include <hip/hip_runtime.h>

#define SIG 2.8853900817779268f   // 2*log2(e)
#define INV_SIG3 (1.0f/(SIG*SIG*SIG))

typedef float float2v __attribute__((ext_vector_type(2)));

__device__ __forceinline__ float rcp_f (float x){ return __builtin_amdgcn_rcpf(x);  }
__device__ __forceinline__ float exp2_f(float x){ return __builtin_amdgcn_exp2f(x); }
__device__ __forceinline__ float2v fma2(float2v a, float2v b, float2v c){
    return __builtin_elementwise_fma(a, b, c);   // -> v_pk_fma_f32
}

// permuted column pair j (0..7): original units (4*(j/2)+(j&1), +2)
#define KC0(j) (4*((j)>>1) + ((j)&1))
#define KC1(j) (KC0(j) + 2)
#define LD2(base, j) ((float2v){ (base)[KC0(j)], (base)[KC1(j)] })

// Block: 448 threads = 7 waves; wave s handles permutation s for 64 consecutive m.
__global__ __launch_bounds__(448) void maron_kernel(
    const float* __restrict__ x,      // (64,14,1024)
    const float* __restrict__ W1,     // (14,16)
    const float* __restrict__ b1,     // (16)
    const float* __restrict__ W2,     // (16,1)
    const float* __restrict__ b2p,    // (1)
    const float* __restrict__ fW1,    // (120,16)
    const float* __restrict__ fb1,    // (16)
    const float* __restrict__ fW2,    // (16,1)
    const float* __restrict__ fb2p,   // (1)
    float* __restrict__ out,          // (M) out ++ (M) L
    int M)
{
    __shared__ float red[7][64][17];  // stride 17 (odd) -> conflict-free

    const int tid = threadIdx.x;
    const int s   = tid >> 6;         // 0..6 (wave-uniform)
    const int ml  = tid & 63;
    const int m   = blockIdx.x * 64 + ml;
    const int bb  = m >> 10, tt = m & 1023;

    const float* xb = x + (size_t)bb * 14 * 1024 + tt;
    const int i0 = (7 - s) % 7;
    const int i1 = (8 - s) % 7;

    const float u = xb[(i0    ) * 1024];
    const float v = xb[(i1    ) * 1024];
    const float w = xb[(7 + i0) * 1024];
    float z = fmaxf(xb[(7 + i1) * 1024], 3.814697265625e-6f);  // 2^-18
    const float rz = rcp_f(z);
    const float wz = w * rz;

    const float* W1r1 = W1 + 1*16;
    const float* W7r  = W1 + 7*16;
    const float* W8r  = W1 + 8*16;

    float C2 = b2p[0];
#pragma unroll
    for (int k = 0; k < 16; ++k) C2 += W2[k];

    // AB2[j] = SIG*(b1 + sum_{rows != 7,8} W1[row,k]*p_row), permuted pair layout.
    float2v AB2[8];
#pragma unroll
    for (int j = 0; j < 8; ++j) {
        float2v t;
#pragma unroll
        for (int h = 0; h < 2; ++h) {
            const int k = KC0(j) + 2*h;
            float tt2 = b1[k] + W1[0*16+k] + W1[1*16+k];
            tt2 += W1[2*16+k] + W1[3*16+k] + W1[4*16+k] + W1[5*16+k] + W1[6*16+k];
            tt2 += W1[9*16+k] + W1[10*16+k] + W1[11*16+k] + W1[12*16+k] + W1[13*16+k];
            t[h] = SIG * tt2;
        }
        AB2[j] = t;
    }

    float2v acc2[8];
#pragma unroll
    for (int j = 0; j < 8; ++j) acc2[j] = (float2v){0.f, 0.f};
    float Lsum = 0.f;

    const float z2t = z * z, z4t = z2t * z2t;
    float zna = SIG * (z4t * z2t * z);  // SIG * z^(7-a)
    float spa = SIG;                    // SIG * u^a
    float spb = SIG;                    // SIG * v^b
    float znb = zna;                    // SIG * z^(7-a-b)

    const float2v w2v  = {w,  w};
    const float2v rz2v = {rz, rz};

    int r = 0;
    for (int a = 0; a <= 7; ++a) {
        for (int bi = 0; bi <= 7 - a; ++bi) {
            const int cmax = 7 - a - bi;
            float2v spc2 = {SIG, SIG};          // SIG * w^c
            float2v spd2 = {znb, znb};          // SIG * z^d
            float mulT = ((spa * spb) * znb) * INV_SIG3;  // u^a v^b w^c z^d

            for (int ci = 0; ci <= cmax; ++ci, ++r) {
                const float2v* frow2 = (const float2v*)(fW1 + (r << 4)); // uniform

                float2v s2p = {0.f, 0.f};
#pragma unroll
                for (int q = 0; q < 4; ++q) {
                    const int jP = 2*q, jQ = 2*q + 1;
                    const float2v tP = fma2(spd2, LD2(W8r, jP), fma2(spc2, LD2(W7r, jP), AB2[jP]));
                    const float2v tQ = fma2(spd2, LD2(W8r, jQ), fma2(spc2, LD2(W7r, jQ), AB2[jQ]));
                    float2v eP = { exp2_f(tP.x), exp2_f(tP.y) };
                    float2v eQ = { exp2_f(tQ.x), exp2_f(tQ.y) };
                    eP += 1.f;                      // pk_add, inline 1.0
                    eQ += 1.f;
                    const float2v W2P = LD2(W2, jP);
                    const float2v W2Q = LD2(W2, jQ);
                    const float2v npair = fma2(W2Q, eP, W2P * eQ);
                    const float2v dpair = eP * eQ;
                    const float2v rpair = { rcp_f(dpair.x), rcp_f(dpair.y) };
                    s2p = fma2(npair, rpair, s2p);
                }
                const float mulnn = fmaf(-2.f, s2p.x + s2p.y, C2);
                Lsum += fabsf(mulT - mulnn);

                const float2v mul2 = {mulnn, mulnn};
#pragma unroll
                for (int j = 0; j < 8; ++j)
                    acc2[j] = fma2(mul2, frow2[j], acc2[j]);

                spc2 *= w2v;
                spd2 *= rz2v;
                mulT *= wz;
            }

            // b -> b+1
            const float dspb = spb * (v - 1.f);
            const float2v dspb2 = {dspb, dspb};
#pragma unroll
            for (int j = 0; j < 8; ++j) AB2[j] = fma2(dspb2, LD2(W1r1, j), AB2[j]);
            spb *= v;
            znb *= rz;
        }
        // a -> a+1 (reset b-contribution to SIG)
        const float dspa = spa * (u - 1.f);
        const float dB   = SIG - spb;
        const float2v dspa2 = {dspa, dspa};
        const float2v dB2   = {dB,   dB};
#pragma unroll
        for (int j = 0; j < 8; ++j)
            AB2[j] = fma2(dspa2, LD2(W1, j), fma2(dB2, LD2(W1r1, j), AB2[j]));
        spa *= u;
        zna *= rz;
        spb = SIG;
        znb = zna;
    }

#pragma unroll
    for (int j = 0; j < 8; ++j) {
        red[s][ml][2*j]   = acc2[j].x;
        red[s][ml][2*j+1] = acc2[j].y;
    }
    red[s][ml][16] = Lsum;
    __syncthreads();

    // parallel 7-way reduction: 64*17 slots over 448 threads
    for (int p = tid; p < 64 * 17; p += 448) {
        const int kk = p >> 6;
        const int mm = p & 63;
        float t = red[0][mm][kk];
#pragma unroll
        for (int ss = 1; ss < 7; ++ss) t += red[ss][mm][kk];
        red[0][mm][kk] = t;
    }
    __syncthreads();

    if (tid < 64) {
        float o = fb2p[0];
        float s3 = 0.f;
#pragma unroll
        for (int k = 0; k < 16; ++k) {
            const float a2 = SIG * (red[0][tid][k] + fb1[k]);
            const float rk = rcp_f(exp2_f(a2) + 1.f);
            s3 = fmaf(fW2[k], rk, s3);
            o += fW2[k];
        }
        o = fmaf(-2.f, s3, o);

        const int mo = blockIdx.x * 64 + tid;
        out[mo]     = o;
        out[M + mo] = red[0][tid][16] * (1.f / 120.f);
    }
}

extern "C" void kernel_launch(void* const* d_in, const int* in_sizes, int n_in,
                              void* d_out, int out_size, void* d_ws, size_t ws_size,
                              hipStream_t stream) {
    const float* x   = (const float*)d_in[0];
    const float* W1  = (const float*)d_in[1];
    const float* b1  = (const float*)d_in[2];
    const float* W2  = (const float*)d_in[3];
    const float* b2  = (const float*)d_in[4];
    const float* fW1 = (const float*)d_in[5];
    const float* fb1 = (const float*)d_in[6];
    const float* fW2 = (const float*)d_in[7];
    const float* fb2 = (const float*)d_in[8];

    const int M = out_size / 2;           // 65536
    const int blocks = M / 64;            // 1024

    maron_kernel<<<blocks, 448, 0, stream>>>(x, W1, b1, W2, b2, fW1, fb1, fW2, fb2,
                                             (float*)d_out, M);
}